// Round 12
// baseline (110.587 us; speedup 1.0000x reference)
//
#include <hip/hip_runtime.h>
#include <hip/hip_bf16.h>

typedef __attribute__((ext_vector_type(8))) short bf16x8;
typedef __attribute__((ext_vector_type(4))) float f32x4;

#define CIN   128
#define COUT  256
#define NIMG  32
#define HWDIM 56
#define HPAD  58
#define KTOT  1152            // 9*128
#define HWIMG 3136
#define MTOT  100352
#define BK    64
#define NT    18
#define NS    36              // 32-k chunks (1152/32)

__device__ __forceinline__ void gload16(const void* g, void* l) {
  __builtin_amdgcn_global_load_lds((const __attribute__((address_space(1))) void*)g,
                                   (__attribute__((address_space(3))) void*)l,
                                   16, 0, 0);
}

// ---------------- fused pre-pass: halo zero + x->NHWC bf16 + packed sign(w)
// Weight packing (R6-verified MFMA fragment order): cout c, k = tap*128+cin:
//   frag F = c>>4, chunk S = k>>5, lane = (c&15) + 16*((k>>3)&3), j = k&7
//   wtf[((F*NS + S)*64 + lane)*8 + j]
__global__ __launch_bounds__(256)
void prep_all(const float* __restrict__ x, const float* __restrict__ w,
              __hip_bfloat16* __restrict__ xp, __hip_bfloat16* __restrict__ wtf) {
  __shared__ float tile[CIN * 57];
  const int bid = blockIdx.x;
  const int t = threadIdx.x;
  if (bid < NIMG * HPAD) {
    const int n = bid / HPAD;
    const int h = bid - n * HPAD;
    __hip_bfloat16* dstrow = xp + ((size_t)n * HPAD + h) * HPAD * CIN;
    int4 z; z.x = 0; z.y = 0; z.z = 0; z.w = 0;
    if (h == 0 || h == HPAD - 1) {
      for (int i = t; i < (HPAD * CIN) / 8; i += 256)
        reinterpret_cast<int4*>(dstrow)[i] = z;
      return;
    }
    const float* src = x + (size_t)n * CIN * HWIMG + (size_t)(h - 1) * HWDIM;
    for (int i = t; i < CIN * HWDIM; i += 256) {
      int c = i / HWDIM;
      int wd = i - c * HWDIM;
      tile[c * 57 + wd] = src[(size_t)c * HWIMG + wd];
    }
    if (t < 32) {
      int side = t >> 4;
      reinterpret_cast<int4*>(dstrow + (side ? (HPAD - 1) : 0) * CIN)[t & 15] = z;
    }
    __syncthreads();
    __hip_bfloat16* dst = dstrow + CIN;
    for (int o = t; o < HWDIM * 64; o += 256) {
      int wd = o >> 6;
      int c = (o & 63) * 2;
      __hip_bfloat162 pr;
      pr.x = __float2bfloat16(tile[c * 57 + wd]);
      pr.y = __float2bfloat16(tile[(c + 1) * 57 + wd]);
      *reinterpret_cast<__hip_bfloat162*>(dst + (size_t)wd * CIN + c) = pr;
    }
  } else {
    int o = (bid - NIMG * HPAD) * 256 + t;
    int cout = o / KTOT;
    int k = o - cout * KTOT;
    int tap = k >> 7;
    int cin = k & 127;
    float v = w[((size_t)cout * CIN + cin) * 9 + tap];
    int dst = (((cout >> 4) * NS + (k >> 5)) * 64 + (cout & 15) + (((k >> 3) & 3) << 4)) * 8 + (k & 7);
    wtf[dst] = __float2bfloat16(v > 0.f ? 1.f : (v < 0.f ? -1.f : 0.f));
  }
}

// ---------------- main: 128x128, R5 B-schedule, A direct global->reg ------
// A prefetch issued right AFTER the drain barrier, BEFORE the MFMA cluster:
// its L2 latency hides under the MFMA; the NEXT step's drain guarantees
// arrival (no separate vmcnt bookkeeping). launch_bounds(256,2): no spill.
__global__ __launch_bounds__(256, 2)
void bconv(const short* __restrict__ xp, const short* __restrict__ wtf,
           const float* __restrict__ bias, float* __restrict__ out) {
  __shared__ short lx[128 * BK];   // 16 KB (B: x only)

  const int tid  = threadIdx.x;
  const int lane = tid & 63;
  const int wv   = tid >> 6;      // 0..3
  const int wm   = wv >> 1;       // cout half
  const int wn   = wv & 1;        // spatial half

  // bijective XCD swizzle (1568 % 8 == 0): L2 locality for xp
  const int myid = blockIdx.y * 784 + blockIdx.x;
  const int sid  = (myid & 7) * 196 + (myid >> 3);
  const int s0   = (sid >> 1) * 128;
  const int f0   = (sid & 1) * 128;

  // B staging: 8 threads/row, 32 rows/round, 4 rounds; swizzled global source
  const int srow = tid >> 3;
  const int slot = tid & 7;
  const int swz  = slot ^ (srow & 7);

  int xoff[4];
#pragma unroll
  for (int r = 0; r < 4; ++r) {
    int m  = s0 + r * 32 + srow;
    int n  = m / HWIMG;
    int hw = m - n * HWIMG;
    int h  = hw / HWDIM;
    int w  = hw - h * HWDIM;
    xoff[r] = ((n * HPAD + h) * HPAD + w) * CIN + swz * 8;
  }

  // A fragments: frag F = f0/16 + wm*4 + f; chunk = 512 shorts (64 lanes x 8)
  const short* wbase = wtf + (size_t)((f0 >> 4) + wm * 4) * NS * 512 + lane * 8;

  f32x4 acc[4][4] = {};
  bf16x8 afP[4][2], afQ[4][2];

#define XKO(T) ((((T) >> 1) / 3 * HPAD + ((T) >> 1) % 3) * CIN + ((T) & 1) * BK)
#define STAGE_B(T) \
  _Pragma("unroll") for (int r = 0; r < 4; ++r) \
    gload16(xp + xoff[r] + XKO(T), &lx[(r * 32 + wv * 8) * BK]);
#define AF_LOAD(DST, T) \
  _Pragma("unroll") for (int f = 0; f < 4; ++f) \
  _Pragma("unroll") for (int ks = 0; ks < 2; ++ks) \
    DST[f][ks] = *(const bf16x8*)(wbase + ((size_t)f * NS + (T) * 2 + ks) * 512);

  const int rlo = lane & 15;
  const int kq  = lane >> 4;
  const int swr = rlo & 7;

  // One K-step: R5's 2-barrier schedule; af(t+1) issued before the MFMA
  // cluster so its latency hides under ~620 cyc of MFMA; next step's drain
  // barrier guarantees its arrival before use.
#define STEP(T, AFU, AFN) { \
    __builtin_amdgcn_s_barrier(); \
    STAGE_B(T) \
    asm volatile("s_waitcnt vmcnt(0)" ::: "memory"); \
    __builtin_amdgcn_s_barrier(); \
    if ((T) + 1 < NT) { AF_LOAD(AFN, (T) + 1) } \
    _Pragma("unroll") for (int ksub = 0; ksub < 2; ++ksub) { \
      const int sx = (ksub * 4 + kq) ^ swr; \
      bf16x8 bx[4]; \
      _Pragma("unroll") for (int f = 0; f < 4; ++f) \
        bx[f] = *(const bf16x8*)&lx[(wn * 64 + f * 16 + rlo) * BK + sx * 8]; \
      _Pragma("unroll") for (int fm = 0; fm < 4; ++fm) \
      _Pragma("unroll") for (int fn = 0; fn < 4; ++fn) \
        acc[fm][fn] = __builtin_amdgcn_mfma_f32_16x16x32_bf16( \
            bx[fn], AFU[fm][ksub], acc[fm][fn], 0, 0, 0); \
    } \
  }

  // prologue: af(0) in regs
  AF_LOAD(afP, 0)

  for (int t = 0; t < NT; t += 2) {
    STEP(t,     afP, afQ)
    STEP(t + 1, afQ, afP)
  }

  // epilogue: D rows = spatial (rg*4+j consecutive hw), cols = cout (lane&15)
  const int col = lane & 15;
  const int rg  = lane >> 4;
  int nb[4], hwb[4];
#pragma unroll
  for (int fn = 0; fn < 4; ++fn) {
    int m16 = s0 + wn * 64 + fn * 16;    // 16-aligned; 3136 % 16 == 0
    int n = m16 / HWIMG;
    nb[fn]  = n;
    hwb[fn] = m16 - n * HWIMG + rg * 4;
  }
#pragma unroll
  for (int fm = 0; fm < 4; ++fm) {
    int cc = f0 + wm * 64 + fm * 16 + col;
    float bv = bias[cc];
#pragma unroll
    for (int fn = 0; fn < 4; ++fn) {
      float4 v;
      v.x = acc[fm][fn][0] + bv;
      v.y = acc[fm][fn][1] + bv;
      v.z = acc[fm][fn][2] + bv;
      v.w = acc[fm][fn][3] + bv;
      *reinterpret_cast<float4*>(out + ((size_t)nb[fn] * COUT + cc) * HWIMG + hwb[fn]) = v;
    }
  }
#undef XKO
#undef STAGE_B
#undef AF_LOAD
#undef STEP
}

extern "C" void kernel_launch(void* const* d_in, const int* in_sizes, int n_in,
                              void* d_out, int out_size, void* d_ws, size_t ws_size,
                              hipStream_t stream) {
  const float* x = (const float*)d_in[0];
  const float* w = (const float*)d_in[1];
  const float* b = (const float*)d_in[2];
  float* out = (float*)d_out;

  const size_t xp_elems = (size_t)NIMG * HPAD * HPAD * CIN;
  __hip_bfloat16* xp  = (__hip_bfloat16*)d_ws;
  __hip_bfloat16* wtf = xp + xp_elems;

  prep_all<<<NIMG * HPAD + (COUT * KTOT) / 256, 256, 0, stream>>>(x, w, xp, wtf);

  dim3 grid(MTOT / 128, COUT / 128);
  bconv<<<grid, 256, 0, stream>>>((const short*)xp, (const short*)wtf, b, out);
}

// Round 13
// 89.161 us; speedup vs baseline: 1.2403x; 1.2403x over previous
//
#include <hip/hip_runtime.h>
#include <hip/hip_bf16.h>

typedef __attribute__((ext_vector_type(8))) short bf16x8;
typedef __attribute__((ext_vector_type(4))) float f32x4;

#define CIN   128
#define COUT  256
#define NIMG  32
#define HWDIM 56
#define HPAD  58
#define KTOT  1152            // 9*128
#define HWIMG 3136
#define MTOT  100352
#define BK    64
#define NT    18

__device__ __forceinline__ void gload16(const void* g, void* l) {
  __builtin_amdgcn_global_load_lds((const __attribute__((address_space(1))) void*)g,
                                   (__attribute__((address_space(3))) void*)l,
                                   16, 0, 0);
}

// ---------------- fused pre-pass: halo zero + x->NHWC bf16 + sign(w) ------
// (R11's vectorized variant: short8 xp stores)
__global__ __launch_bounds__(256)
void prep_all(const float* __restrict__ x, const float* __restrict__ w,
              __hip_bfloat16* __restrict__ xp, __hip_bfloat16* __restrict__ wt) {
  __shared__ float tile[CIN * 57];
  const int bid = blockIdx.x;
  const int t = threadIdx.x;
  if (bid < NIMG * HPAD) {
    const int n = bid / HPAD;
    const int h = bid - n * HPAD;
    __hip_bfloat16* dstrow = xp + ((size_t)n * HPAD + h) * HPAD * CIN;
    int4 z; z.x = 0; z.y = 0; z.z = 0; z.w = 0;
    if (h == 0 || h == HPAD - 1) {          // full halo row
      for (int i = t; i < (HPAD * CIN) / 8; i += 256)
        reinterpret_cast<int4*>(dstrow)[i] = z;
      return;
    }
    const float* src = x + (size_t)n * CIN * HWIMG + (size_t)(h - 1) * HWDIM;
    for (int i = t; i < CIN * HWDIM; i += 256) {
      int c = i / HWDIM;
      int wd = i - c * HWDIM;
      tile[c * 57 + wd] = src[(size_t)c * HWIMG + wd];
    }
    if (t < 32) {                            // halo cols 0 and 57
      int side = t >> 4;
      reinterpret_cast<int4*>(dstrow + (side ? (HPAD - 1) : 0) * CIN)[t & 15] = z;
    }
    __syncthreads();
    // vectorized xp writes: short8 (16B) per (wd, 8-channel chunk)
    __hip_bfloat16* dst = dstrow + CIN;      // col 1
    for (int o = t; o < HWDIM * 16; o += 256) {
      int wd = o >> 4;
      int c8 = (o & 15) * 8;
      bf16x8 v;
#pragma unroll
      for (int j = 0; j < 8; ++j)
        v[j] = (short)__bfloat16_as_ushort(__float2bfloat16(tile[(c8 + j) * 57 + wd]));
      *reinterpret_cast<bf16x8*>(dst + (size_t)wd * CIN + c8) = v;
    }
  } else {
    int o = (bid - NIMG * HPAD) * 256 + t;
    int cout = o / KTOT;
    int r = o - cout * KTOT;
    int tap = r >> 7;
    int cin = r & 127;
    float v = w[((size_t)cout * CIN + cin) * 9 + tap];
    wt[o] = __float2bfloat16(v > 0.f ? 1.f : (v < 0.f ? -1.f : 0.f));
  }
}

// ---------------- main: 128x128 tile, BK=64 (R5, the measured best) -------
__global__ __launch_bounds__(256, 4)
void bconv(const short* __restrict__ xp, const short* __restrict__ wt,
           const float* __restrict__ bias, float* __restrict__ out) {
  __shared__ short lw[128 * BK];   // 16 KB (A: weights)
  __shared__ short lx[128 * BK];   // 16 KB (B: x)

  const int tid  = threadIdx.x;
  const int lane = tid & 63;
  const int wv   = tid >> 6;      // 0..3
  const int wm   = wv >> 1;       // cout half
  const int wn   = wv & 1;        // spatial half

  // bijective XCD swizzle (1568 % 8 == 0): L2 locality for xp
  const int myid = blockIdx.y * 784 + blockIdx.x;
  const int sid  = (myid & 7) * 196 + (myid >> 3);
  const int s0   = (sid >> 1) * 128;
  const int f0   = (sid & 1) * 128;

  // staging: 8 threads/row, 32 rows/round, 4 rounds; swizzled global source
  const int srow = tid >> 3;      // 0..31
  const int slot = tid & 7;
  const int swz  = slot ^ (srow & 7);

  int xoff[4];
  int woff[4];
#pragma unroll
  for (int r = 0; r < 4; ++r) {
    int m  = s0 + r * 32 + srow;
    int n  = m / HWIMG;
    int hw = m - n * HWIMG;
    int h  = hw / HWDIM;
    int w  = hw - h * HWDIM;
    xoff[r] = ((n * HPAD + h) * HPAD + w) * CIN + swz * 8;
    woff[r] = (f0 + r * 32 + srow) * KTOT + swz * 8;
  }

  f32x4 acc[4][4] = {};

  short* lwdst = &lw[(wv * 8) * BK];
  short* lxdst = &lx[(wv * 8) * BK];

  for (int ks = 0; ks < NT; ++ks) {
    const int tap = ks >> 1;
    const int kh  = tap / 3;
    const int kw  = tap - kh * 3;
    const int xko = (kh * HPAD + kw) * CIN + (ks & 1) * BK;
    const int wko = ks * BK;

    __syncthreads();
#pragma unroll
    for (int r = 0; r < 4; ++r) {
      gload16(wt + woff[r] + wko, lwdst + r * 32 * BK);
      gload16(xp + xoff[r] + xko, lxdst + r * 32 * BK);
    }
    __syncthreads();

    const int rlo = lane & 15;
#pragma unroll
    for (int ksub = 0; ksub < 2; ++ksub) {
      const int sx = (ksub * 4 + (lane >> 4)) ^ (rlo & 7);
      bf16x8 af[4], bx[4];
#pragma unroll
      for (int f = 0; f < 4; ++f)
        af[f] = *(const bf16x8*)&lw[(wm * 64 + f * 16 + rlo) * BK + sx * 8];
#pragma unroll
      for (int f = 0; f < 4; ++f)
        bx[f] = *(const bf16x8*)&lx[(wn * 64 + f * 16 + rlo) * BK + sx * 8];
      // swapped operands: D rows = spatial (bx), cols = cout (af)
#pragma unroll
      for (int fm = 0; fm < 4; ++fm)
#pragma unroll
        for (int fn = 0; fn < 4; ++fn)
          acc[fm][fn] = __builtin_amdgcn_mfma_f32_16x16x32_bf16(
              bx[fn], af[fm], acc[fm][fn], 0, 0, 0);
    }
  }

  // epilogue: D rows = spatial (rg*4+j consecutive hw), cols = cout (lane&15)
  const int col = lane & 15;
  const int rg  = lane >> 4;
  int nb[4], hwb[4];
#pragma unroll
  for (int fn = 0; fn < 4; ++fn) {
    int m16 = s0 + wn * 64 + fn * 16;    // 16-aligned; 3136 % 16 == 0
    int n = m16 / HWIMG;
    nb[fn]  = n;
    hwb[fn] = m16 - n * HWIMG + rg * 4;
  }
#pragma unroll
  for (int fm = 0; fm < 4; ++fm) {
    int cc = f0 + wm * 64 + fm * 16 + col;
    float bv = bias[cc];
#pragma unroll
    for (int fn = 0; fn < 4; ++fn) {
      float4 v;
      v.x = acc[fm][fn][0] + bv;
      v.y = acc[fm][fn][1] + bv;
      v.z = acc[fm][fn][2] + bv;
      v.w = acc[fm][fn][3] + bv;
      *reinterpret_cast<float4*>(out + ((size_t)nb[fn] * COUT + cc) * HWIMG + hwb[fn]) = v;
    }
  }
}

extern "C" void kernel_launch(void* const* d_in, const int* in_sizes, int n_in,
                              void* d_out, int out_size, void* d_ws, size_t ws_size,
                              hipStream_t stream) {
  const float* x = (const float*)d_in[0];
  const float* w = (const float*)d_in[1];
  const float* b = (const float*)d_in[2];
  float* out = (float*)d_out;

  const size_t xp_elems = (size_t)NIMG * HPAD * HPAD * CIN;
  __hip_bfloat16* xp = (__hip_bfloat16*)d_ws;
  __hip_bfloat16* wt = xp + xp_elems;

  prep_all<<<NIMG * HPAD + (COUT * KTOT) / 256, 256, 0, stream>>>(x, w, xp, wt);

  dim3 grid(MTOT / 128, COUT / 128);
  bconv<<<grid, 256, 0, stream>>>((const short*)xp, (const short*)wt, b, out);
}